// Round 1
// baseline (319.912 us; speedup 1.0000x reference)
//
#include <hip/hip_runtime.h>

// B=4, T=2048, C=1024, H=16, D=64.  M = B*T = 8192.
// Pipeline: cast f32->bf16; QKV GEMM (bf16 MFMA); V transpose; causal flash attention; out GEMM + bias.

typedef __attribute__((ext_vector_type(8))) __bf16 bf16x8;
typedef __attribute__((ext_vector_type(4))) float f32x4;

__device__ __forceinline__ unsigned short f2bf(float f) {
  union { float f; unsigned u; } v; v.f = f;
  unsigned r = v.u + 0x7fffu + ((v.u >> 16) & 1u);   // RNE
  return (unsigned short)(r >> 16);
}

__device__ __forceinline__ void gld16(const void* g, void* l) {
  __builtin_amdgcn_global_load_lds(
      (const __attribute__((address_space(1))) void*)g,
      (__attribute__((address_space(3))) void*)l, 16, 0, 0);
}

__device__ __forceinline__ f32x4 mfma16(bf16x8 a, bf16x8 b, f32x4 c) {
  return __builtin_amdgcn_mfma_f32_16x16x32_bf16(a, b, c, 0, 0, 0);
}

__global__ __launch_bounds__(256) void cast_f32_bf16(
    const float* __restrict__ src, unsigned short* __restrict__ dst, int n) {
  int i = (blockIdx.x * 256 + threadIdx.x) * 4;
  if (i >= n) return;
  float4 v = *(const float4*)(src + i);
  ushort4 o;
  o.x = f2bf(v.x); o.y = f2bf(v.y); o.z = f2bf(v.z); o.w = f2bf(v.w);
  *(ushort4*)(dst + i) = o;
}

// C[m][n] = sum_k A[m][k] * Bm[n][k]; A:[?][1024] bf16, Bm:[N][1024] bf16.
// 128x128 tile, BK=64, 4 waves (2x2), each wave 4x4 tiles of 16x16x32 MFMA.
// MODE 0: QKV epilogue -> scatter to q/k/v [B,H,T,D], q scaled 0.125.
// MODE 1: out = acc + bias[n], f32.
template <int MODE>
__global__ __launch_bounds__(256) void gemm_bt(
    const unsigned short* __restrict__ A, const unsigned short* __restrict__ Bm,
    unsigned short* __restrict__ qo, unsigned short* __restrict__ ko,
    unsigned short* __restrict__ vo,
    const float* __restrict__ bias, float* __restrict__ fout) {
  __shared__ unsigned short Al[128 * 64];
  __shared__ unsigned short Bl[128 * 64];
  const int tid = threadIdx.x;
  const int w = tid >> 6, l = tid & 63, lr = l & 15, lg = l >> 4;
  const int m0 = blockIdx.y * 128, n0 = blockIdx.x * 128;
  const int wm = w >> 1, wn = w & 1;
  f32x4 acc[4][4];
  f32x4 zero = {0.f, 0.f, 0.f, 0.f};
#pragma unroll
  for (int i = 0; i < 4; i++)
#pragma unroll
    for (int j = 0; j < 4; j++) acc[i][j] = zero;

  for (int kk = 0; kk < 1024; kk += 64) {
    // stage A[128][64], B[128][64] linear into LDS via global_load_lds (16B/lane)
#pragma unroll
    for (int c = 0; c < 4; c++) {
      int e = c * 2048 + tid * 8;
      int r = e >> 6, col = e & 63;
      gld16(A + (size_t)(m0 + r) * 1024 + kk + col, (char*)Al + (size_t)e * 2);
      gld16(Bm + (size_t)(n0 + r) * 1024 + kk + col, (char*)Bl + (size_t)e * 2);
    }
    __syncthreads();   // drains vmcnt before barrier (compiler-inserted)
#pragma unroll
    for (int c = 0; c < 2; c++) {
      bf16x8 af[4], bfr[4];
#pragma unroll
      for (int mt = 0; mt < 4; mt++)
        af[mt] = *(const bf16x8*)(Al + (wm * 64 + mt * 16 + lr) * 64 + c * 32 + lg * 8);
#pragma unroll
      for (int nt = 0; nt < 4; nt++)
        bfr[nt] = *(const bf16x8*)(Bl + (wn * 64 + nt * 16 + lr) * 64 + c * 32 + lg * 8);
#pragma unroll
      for (int mt = 0; mt < 4; mt++)
#pragma unroll
        for (int nt = 0; nt < 4; nt++)
          acc[mt][nt] = mfma16(af[mt], bfr[nt], acc[mt][nt]);
    }
    __syncthreads();
  }

  // epilogue; C layout: col = lane&15, row = (lane>>4)*4 + i
#pragma unroll
  for (int mt = 0; mt < 4; mt++) {
#pragma unroll
    for (int nt = 0; nt < 4; nt++) {
      int n = n0 + wn * 64 + nt * 16 + lr;
      int mbase = m0 + wm * 64 + mt * 16 + lg * 4;
      if (MODE == 0) {
        int ty = n >> 10, cc = n & 1023;
        int h = cc >> 6, dd = cc & 63;
        unsigned short* dst = (ty == 0) ? qo : ((ty == 1) ? ko : vo);
        float sc = (ty == 0) ? 0.125f : 1.0f;   // fold 1/sqrt(D) into q
#pragma unroll
        for (int i = 0; i < 4; i++) {
          int m = mbase + i;
          int b = m >> 11, tt = m & 2047;
          dst[(((size_t)(b * 16 + h)) * 2048 + tt) * 64 + dd] =
              f2bf(acc[mt][nt][i] * sc);
        }
      } else {
        float bv = bias[n];
#pragma unroll
        for (int i = 0; i < 4; i++) {
          int m = mbase + i;
          fout[(size_t)m * 1024 + n] = acc[mt][nt][i] + bv;
        }
      }
    }
  }
}

// v [B,H,T,D] -> vt [B,H,D,T], 64x64 tiles via LDS
__global__ __launch_bounds__(256) void transpose_v64(
    const unsigned short* __restrict__ v, unsigned short* __restrict__ vt) {
  __shared__ unsigned short tile[64 * 72];
  int bh = blockIdx.y, t0 = blockIdx.x * 64;
  const unsigned short* vp = v + (size_t)bh * 2048 * 64;
  unsigned short* vtp = vt + (size_t)bh * 64 * 2048;
  int tid = threadIdx.x;
#pragma unroll
  for (int it = 0; it < 2; ++it) {
    int s = tid + it * 256;
    int r = s >> 3, c = (s & 7) * 8;
    *(uint4*)(tile + r * 72 + c) = *(const uint4*)(vp + (size_t)(t0 + r) * 64 + c);
  }
  __syncthreads();
#pragma unroll
  for (int it = 0; it < 2; ++it) {
    int s = tid + it * 256;
    int d = s >> 3, c = (s & 7) * 8;   // c = t-col within tile
    unsigned short tmp[8];
#pragma unroll
    for (int j = 0; j < 8; j++) tmp[j] = tile[(c + j) * 72 + d];
    *(uint4*)(vtp + (size_t)d * 2048 + t0 + c) = *(uint4*)tmp;
  }
}

// Causal flash attention. Block: 4 waves, 64 q rows (16/wave). KV tiles of 64.
// q pre-scaled by 1/8. q,k: [B,H,T,D]; vt: [B,H,D,T]; og: [B,T,C] bf16.
__global__ __launch_bounds__(256) void attn_causal(
    const unsigned short* __restrict__ qg, const unsigned short* __restrict__ kg,
    const unsigned short* __restrict__ vtg, unsigned short* __restrict__ og) {
  __shared__ unsigned short Kl[64 * 72];
  __shared__ unsigned short Vl[64 * 72];
  __shared__ unsigned short Pl[4 * 16 * 72];
  const int bh = blockIdx.y;
  const int q0 = blockIdx.x * 64;
  const int b = bh >> 4, h = bh & 15;
  const unsigned short* qp = qg + (size_t)bh * 2048 * 64;
  const unsigned short* kp = kg + (size_t)bh * 2048 * 64;
  const unsigned short* vp = vtg + (size_t)bh * 64 * 2048;
  const int tid = threadIdx.x, w = tid >> 6, l = tid & 63, lr = l & 15, lg = l >> 4;

  // Q A-frags hoisted: lane holds Q[w*16 + lr][lg*8 .. +7] and +32
  bf16x8 qf0, qf1;
  {
    const unsigned short* qrow = qp + (size_t)(q0 + w * 16 + lr) * 64 + lg * 8;
    qf0 = *(const bf16x8*)(qrow);
    qf1 = *(const bf16x8*)(qrow + 32);
  }
  f32x4 o[4];
  f32x4 zero = {0.f, 0.f, 0.f, 0.f};
#pragma unroll
  for (int dt = 0; dt < 4; dt++) o[dt] = zero;
  float mrow[4], lsum[4];
#pragma unroll
  for (int i = 0; i < 4; i++) { mrow[i] = -1e30f; lsum[i] = 0.f; }

  const int nkv = (q0 >> 6) + 1;
  for (int kt = 0; kt < nkv; ++kt) {
    const int k0 = kt * 64;
    // stage K [64 kv][64 d] and Vt [64 d][64 t] into padded LDS (stride 72)
#pragma unroll
    for (int it = 0; it < 2; ++it) {
      int s = tid + it * 256;
      int r = s >> 3, c = (s & 7) * 8;
      *(uint4*)(Kl + r * 72 + c) = *(const uint4*)(kp + (size_t)(k0 + r) * 64 + c);
      *(uint4*)(Vl + r * 72 + c) = *(const uint4*)(vp + (size_t)r * 2048 + k0 + c);
    }
    __syncthreads();

    // S = Q K^T : 4 tiles of 16x16 along kv
    f32x4 s[4];
#pragma unroll
    for (int a = 0; a < 4; a++) {
      bf16x8 kf0 = *(const bf16x8*)(Kl + (a * 16 + lr) * 72 + lg * 8);
      bf16x8 kf1 = *(const bf16x8*)(Kl + (a * 16 + lr) * 72 + 32 + lg * 8);
      f32x4 z = zero;
      z = mfma16(qf0, kf0, z);
      z = mfma16(qf1, kf1, z);
      s[a] = z;
    }
    if (k0 == q0) {   // diagonal tile: causal mask (only tile where kv can exceed q)
#pragma unroll
      for (int a = 0; a < 4; a++)
#pragma unroll
        for (int i = 0; i < 4; i++) {
          int kvg = k0 + a * 16 + lr;
          int qq = q0 + w * 16 + lg * 4 + i;
          if (kvg > qq) s[a][i] = -1e30f;
        }
    }
    // online softmax, rows live across lanes with same lg (cols = lr)
#pragma unroll
    for (int i = 0; i < 4; i++) {
      float tm = fmaxf(fmaxf(s[0][i], s[1][i]), fmaxf(s[2][i], s[3][i]));
#pragma unroll
      for (int xm = 1; xm < 16; xm <<= 1) tm = fmaxf(tm, __shfl_xor(tm, xm, 64));
      float nm = fmaxf(mrow[i], tm);
      float f = __expf(mrow[i] - nm);
      mrow[i] = nm;
      float ps = 0.f;
#pragma unroll
      for (int a = 0; a < 4; a++) {
        float p = __expf(s[a][i] - nm);
        s[a][i] = p;
        ps += p;
      }
      lsum[i] = lsum[i] * f + ps;   // per-lane partial; reduced at end
#pragma unroll
      for (int dt = 0; dt < 4; dt++) o[dt][i] *= f;
    }
    // P (C-layout) -> LDS -> A-layout frags. Per-wave region, same-wave in-order LDS.
#pragma unroll
    for (int a = 0; a < 4; a++)
#pragma unroll
      for (int i = 0; i < 4; i++)
        Pl[(w * 16 + lg * 4 + i) * 72 + a * 16 + lr] = f2bf(s[a][i]);
    bf16x8 pf0 = *(const bf16x8*)(Pl + (w * 16 + lr) * 72 + lg * 8);
    bf16x8 pf1 = *(const bf16x8*)(Pl + (w * 16 + lr) * 72 + 32 + lg * 8);
#pragma unroll
    for (int dt = 0; dt < 4; dt++) {
      bf16x8 vf0 = *(const bf16x8*)(Vl + (dt * 16 + lr) * 72 + lg * 8);
      bf16x8 vf1 = *(const bf16x8*)(Vl + (dt * 16 + lr) * 72 + 32 + lg * 8);
      o[dt] = mfma16(pf0, vf0, o[dt]);
      o[dt] = mfma16(pf1, vf1, o[dt]);
    }
    __syncthreads();
  }

#pragma unroll
  for (int i = 0; i < 4; i++) {
    float sum = lsum[i];
#pragma unroll
    for (int xm = 1; xm < 16; xm <<= 1) sum += __shfl_xor(sum, xm, 64);
    float inv = 1.0f / sum;
    int t = q0 + w * 16 + lg * 4 + i;
#pragma unroll
    for (int dt = 0; dt < 4; dt++) {
      int cc = h * 64 + dt * 16 + lr;
      og[((size_t)b * 2048 + t) * 1024 + cc] = f2bf(o[dt][i] * inv);
    }
  }
}

extern "C" void kernel_launch(void* const* d_in, const int* in_sizes, int n_in,
                              void* d_out, int out_size, void* d_ws, size_t ws_size,
                              hipStream_t stream) {
  const float* x = (const float*)d_in[0];
  const float* Wqkv = (const float*)d_in[1];
  const float* Wout = (const float*)d_in[2];
  const float* bout = (const float*)d_in[3];
  float* out = (float*)d_out;
  char* ws = (char*)d_ws;

  // ws carve (72 MB): xb(16M, reused as vt) | wqb(6M) | wob(2M) | q(16M) | k(16M) | v(16M, reused as og)
  unsigned short* xb = (unsigned short*)(ws);
  unsigned short* wqb = (unsigned short*)(ws + 16777216);
  unsigned short* wob = (unsigned short*)(ws + 23068672);
  unsigned short* qb = (unsigned short*)(ws + 25165824);
  unsigned short* kb = (unsigned short*)(ws + 41943040);
  unsigned short* vb = (unsigned short*)(ws + 58720256);
  unsigned short* vtb = xb;   // x dead after QKV GEMM
  unsigned short* ogb = vb;   // v dead after transpose

  cast_f32_bf16<<<8192, 256, 0, stream>>>(x, xb, 8388608);
  cast_f32_bf16<<<3072, 256, 0, stream>>>(Wqkv, wqb, 3145728);
  cast_f32_bf16<<<1024, 256, 0, stream>>>(Wout, wob, 1048576);

  gemm_bt<0><<<dim3(24, 64), 256, 0, stream>>>(xb, wqb, qb, kb, vb, nullptr, nullptr);
  transpose_v64<<<dim3(32, 64), 256, 0, stream>>>(vb, vtb);
  attn_causal<<<dim3(32, 64), 256, 0, stream>>>(qb, kb, vtb, ogb);
  gemm_bt<1><<<dim3(8, 64), 256, 0, stream>>>(ogb, wob, nullptr, nullptr, nullptr, bout, out);
}

// Round 2
// 208.071 us; speedup vs baseline: 1.5375x; 1.5375x over previous
//
#include <hip/hip_runtime.h>

// B=4, T=2048, C=1024, H=16, D=64.  M = B*T = 8192.
// cast f32->bf16; QKV GEMM (bf16 MFMA); V transpose; 8-wave 32x32 swapped-operand
// causal flash attention (S^T/O^T, in-register softmax); out GEMM + bias.

typedef __attribute__((ext_vector_type(8))) __bf16 bf16x8;
typedef __attribute__((ext_vector_type(4))) float f32x4;
typedef __attribute__((ext_vector_type(16))) float f32x16;

__device__ __forceinline__ unsigned short f2bf(float f) {
  union { float f; unsigned u; } v; v.f = f;
  unsigned r = v.u + 0x7fffu + ((v.u >> 16) & 1u);   // RNE
  return (unsigned short)(r >> 16);
}

__device__ __forceinline__ unsigned cvtpk(float lo, float hi) {
  unsigned r;
  asm("v_cvt_pk_bf16_f32 %0, %1, %2" : "=v"(r) : "v"(lo), "v"(hi));
  return r;
}

__device__ __forceinline__ void gld16(const void* g, void* l) {
  __builtin_amdgcn_global_load_lds(
      (const __attribute__((address_space(1))) void*)g,
      (__attribute__((address_space(3))) void*)l, 16, 0, 0);
}

__device__ __forceinline__ f32x4 mfma16(bf16x8 a, bf16x8 b, f32x4 c) {
  return __builtin_amdgcn_mfma_f32_16x16x32_bf16(a, b, c, 0, 0, 0);
}
__device__ __forceinline__ f32x16 mfma32(bf16x8 a, bf16x8 b, f32x16 c) {
  return __builtin_amdgcn_mfma_f32_32x32x16_bf16(a, b, c, 0, 0, 0);
}

__global__ __launch_bounds__(256) void cast_f32_bf16(
    const float* __restrict__ src, unsigned short* __restrict__ dst, int n) {
  int i = (blockIdx.x * 256 + threadIdx.x) * 4;
  if (i >= n) return;
  float4 v = *(const float4*)(src + i);
  ushort4 o;
  o.x = f2bf(v.x); o.y = f2bf(v.y); o.z = f2bf(v.z); o.w = f2bf(v.w);
  *(ushort4*)(dst + i) = o;
}

// C[m][n] = sum_k A[m][k]*Bm[n][k].  128x128 tile, BK=64, 4 waves.
// MODE 0: scatter to q/k/v [B,H,T,D], q scaled by 0.125*log2(e) (exp2-domain softmax).
// MODE 1: out = acc + bias[n], f32.
template <int MODE>
__global__ __launch_bounds__(256) void gemm_bt(
    const unsigned short* __restrict__ A, const unsigned short* __restrict__ Bm,
    unsigned short* __restrict__ qo, unsigned short* __restrict__ ko,
    unsigned short* __restrict__ vo,
    const float* __restrict__ bias, float* __restrict__ fout) {
  __shared__ unsigned short Al[128 * 64];
  __shared__ unsigned short Bl[128 * 64];
  const int tid = threadIdx.x;
  const int w = tid >> 6, l = tid & 63, lr = l & 15, lg = l >> 4;
  const int m0 = blockIdx.y * 128, n0 = blockIdx.x * 128;
  const int wm = w >> 1, wn = w & 1;
  f32x4 acc[4][4];
  f32x4 zero = {0.f, 0.f, 0.f, 0.f};
#pragma unroll
  for (int i = 0; i < 4; i++)
#pragma unroll
    for (int j = 0; j < 4; j++) acc[i][j] = zero;

  for (int kk = 0; kk < 1024; kk += 64) {
#pragma unroll
    for (int c = 0; c < 4; c++) {
      int e = c * 2048 + tid * 8;
      int r = e >> 6, col = e & 63;
      gld16(A + (size_t)(m0 + r) * 1024 + kk + col, (char*)Al + (size_t)e * 2);
      gld16(Bm + (size_t)(n0 + r) * 1024 + kk + col, (char*)Bl + (size_t)e * 2);
    }
    __syncthreads();
#pragma unroll
    for (int c = 0; c < 2; c++) {
      bf16x8 af[4], bfr[4];
#pragma unroll
      for (int mt = 0; mt < 4; mt++)
        af[mt] = *(const bf16x8*)(Al + (wm * 64 + mt * 16 + lr) * 64 + c * 32 + lg * 8);
#pragma unroll
      for (int nt = 0; nt < 4; nt++)
        bfr[nt] = *(const bf16x8*)(Bl + (wn * 64 + nt * 16 + lr) * 64 + c * 32 + lg * 8);
#pragma unroll
      for (int mt = 0; mt < 4; mt++)
#pragma unroll
        for (int nt = 0; nt < 4; nt++)
          acc[mt][nt] = mfma16(af[mt], bfr[nt], acc[mt][nt]);
    }
    __syncthreads();
  }

#pragma unroll
  for (int mt = 0; mt < 4; mt++) {
#pragma unroll
    for (int nt = 0; nt < 4; nt++) {
      int n = n0 + wn * 64 + nt * 16 + lr;
      int mbase = m0 + wm * 64 + mt * 16 + lg * 4;
      if (MODE == 0) {
        int ty = n >> 10, cc = n & 1023;
        int h = cc >> 6, dd = cc & 63;
        unsigned short* dst = (ty == 0) ? qo : ((ty == 1) ? ko : vo);
        float sc = (ty == 0) ? 0.18033688011111687f : 1.0f;  // (1/8)*log2(e)
#pragma unroll
        for (int i = 0; i < 4; i++) {
          int m = mbase + i;
          int b = m >> 11, tt = m & 2047;
          dst[(((size_t)(b * 16 + h)) * 2048 + tt) * 64 + dd] =
              f2bf(acc[mt][nt][i] * sc);
        }
      } else {
        float bv = bias[n];
#pragma unroll
        for (int i = 0; i < 4; i++) {
          int m = mbase + i;
          fout[(size_t)m * 1024 + n] = acc[mt][nt][i] + bv;
        }
      }
    }
  }
}

// v [B,H,T,D] -> vt [B,H,D,T]
__global__ __launch_bounds__(256) void transpose_v64(
    const unsigned short* __restrict__ v, unsigned short* __restrict__ vt) {
  __shared__ unsigned short tile[64 * 72];
  int bh = blockIdx.y, t0 = blockIdx.x * 64;
  const unsigned short* vp = v + (size_t)bh * 2048 * 64;
  unsigned short* vtp = vt + (size_t)bh * 64 * 2048;
  int tid = threadIdx.x;
#pragma unroll
  for (int it = 0; it < 2; ++it) {
    int s = tid + it * 256;
    int r = s >> 3, c = (s & 7) * 8;
    *(uint4*)(tile + r * 72 + c) = *(const uint4*)(vp + (size_t)(t0 + r) * 64 + c);
  }
  __syncthreads();
#pragma unroll
  for (int it = 0; it < 2; ++it) {
    int s = tid + it * 256;
    int d = s >> 3, c = (s & 7) * 8;
    unsigned short tmp[8];
#pragma unroll
    for (int j = 0; j < 8; j++) tmp[j] = tile[(c + j) * 72 + d];
    *(uint4*)(vtp + (size_t)d * 2048 + t0 + c) = *(uint4*)tmp;
  }
}

// swizzled LDS read of an MFMA fragment: row stride 128B, byte ^= (row&7)<<4
__device__ __forceinline__ bf16x8 ldsw(const char* base, int row, int cb) {
  return *(const bf16x8*)(base + row * 128 + (cb ^ ((row & 7) << 4)));
}

// Causal flash attention, 8 waves x 32 q-rows (strided: q = q0 + 8*lane + w).
// KV tiles of 64, swapped-operand 32x32x16 MFMA, in-register exp2 softmax.
// q pre-scaled by 0.125*log2e.  q,k: [B,H,T,D]; vt: [B,H,D,T]; og: [B,T,C] bf16.
__global__ __launch_bounds__(512, 4) void attn_causal(
    const unsigned short* __restrict__ qg, const unsigned short* __restrict__ kg,
    const unsigned short* __restrict__ vtg, unsigned short* __restrict__ og) {
  __shared__ char lds[32768];   // dbuf: [K 8K | Vt 8K] x2; reused for out bounce
  const int tid = threadIdx.x;
  const int w = tid >> 6, l = tid & 63, lo = l & 31, hi = l >> 5;
  const int bh = blockIdx.x;
  const int qc = 7 - blockIdx.y;           // LPT: heavy q-chunks dispatch first
  const int q0 = qc * 256;
  const int nkv = qc * 4 + 4;
  const int b = bh >> 4, h = bh & 15;
  const char* kpB = (const char*)(kg + (size_t)bh * 131072);
  const char* vpB = (const char*)(vtg + (size_t)bh * 131072);
  const unsigned short* qp = qg + (size_t)bh * 131072;
  const int qrow = q0 + 8 * lo + w;

  // Q B-frags in registers: lane holds Q[qrow][hi*8 + c*16 .. +8)
  bf16x8 qf[4];
#pragma unroll
  for (int c = 0; c < 4; ++c)
    qf[c] = *(const bf16x8*)(qp + (size_t)qrow * 64 + hi * 8 + c * 16);

  f32x16 ov[2];
#pragma unroll
  for (int r = 0; r < 16; ++r) { ov[0][r] = 0.f; ov[1][r] = 0.f; }
  float m = -__builtin_inff(), lsum = 0.f;

  // staging lane mapping (512 lanes cover one 64x128B tile, source pre-swizzled)
  const int srow = tid >> 3;
  const int scb = ((tid & 7) * 16) ^ ((srow & 7) << 4);

  // prologue: stage tile 0 into buf 0
  gld16(kpB + (size_t)srow * 128 + scb, lds + tid * 16);
  gld16(vpB + (size_t)srow * 4096 + scb, lds + 8192 + tid * 16);
  __syncthreads();

  for (int kt = 0; kt < nkv; ++kt) {
    const int k0 = kt * 64;
    if (kt + 1 < nkv) {   // stage next tile into other buffer (overlaps compute)
      char* nb = lds + ((kt + 1) & 1) * 16384;
      gld16(kpB + (size_t)(k0 + 64 + srow) * 128 + scb, nb + tid * 16);
      gld16(vpB + (size_t)srow * 4096 + (size_t)(k0 + 64) * 2 + scb, nb + 8192 + tid * 16);
    }
    const char* Kbuf = lds + (kt & 1) * 16384;
    const char* Vbuf = Kbuf + 8192;

    // S^T = K·Q^T (two 32-row k blocks, 4 d-chunks)
    f32x16 sv[2];
#pragma unroll
    for (int r = 0; r < 16; ++r) { sv[0][r] = 0.f; sv[1][r] = 0.f; }
#pragma unroll
    for (int c = 0; c < 4; ++c) {
      bf16x8 kf0 = ldsw(Kbuf, lo, hi * 16 + c * 32);
      bf16x8 kf1 = ldsw(Kbuf, 32 + lo, hi * 16 + c * 32);
      sv[0] = mfma32(kf0, qf[c], sv[0]);
      sv[1] = mfma32(kf1, qf[c], sv[1]);
    }

    if (kt >= nkv - 4) {   // causal mask (last 4 tiles only)
#pragma unroll
      for (int t = 0; t < 2; ++t)
#pragma unroll
        for (int r = 0; r < 16; ++r) {
          int kgl = k0 + t * 32 + (r & 3) + 8 * (r >> 2) + 4 * hi;
          if (kgl > qrow) sv[t][r] = -__builtin_inff();
        }
    }

    // online softmax in exp2 domain; q is lane-local (lane pair lo/lo+32 splits k)
    float tm = -__builtin_inff();
#pragma unroll
    for (int t = 0; t < 2; ++t)
#pragma unroll
      for (int r = 0; r < 16; ++r) tm = fmaxf(tm, sv[t][r]);
    tm = fmaxf(tm, __shfl_xor(tm, 32, 64));
    float nm = fmaxf(fmaxf(m, tm), -1e30f);   // clamp: fully-masked lanes stay sane
    float f = exp2f(m - nm);
    m = nm;
    float ps = 0.f;
#pragma unroll
    for (int t = 0; t < 2; ++t)
#pragma unroll
      for (int r = 0; r < 16; ++r) {
        float p = exp2f(sv[t][r] - nm);
        sv[t][r] = p;
        ps += p;
      }
    lsum = lsum * f + ps;
#pragma unroll
    for (int r = 0; r < 16; ++r) { ov[0][r] *= f; ov[1][r] *= f; }

    // P -> bf16 B-frags (cvt_pk + permlane32_swap), then O^T += Vt·P^T
#pragma unroll
    for (int c = 0; c < 4; ++c) {
      const int t = c >> 1, rb = (c & 1) * 8;
      unsigned wA = cvtpk(sv[t][rb + 0], sv[t][rb + 1]);
      unsigned wB = cvtpk(sv[t][rb + 2], sv[t][rb + 3]);
      unsigned wC = cvtpk(sv[t][rb + 4], sv[t][rb + 5]);
      unsigned wD = cvtpk(sv[t][rb + 6], sv[t][rb + 7]);
      asm volatile("v_permlane32_swap_b32 %0, %1" : "+v"(wA), "+v"(wC));
      asm volatile("v_permlane32_swap_b32 %0, %1" : "+v"(wB), "+v"(wD));
      union { uint4 u; bf16x8 h; } pc;
      pc.u.x = wA; pc.u.y = wB; pc.u.z = wC; pc.u.w = wD;
      bf16x8 vf0 = ldsw(Vbuf, lo, hi * 16 + c * 32);
      bf16x8 vf1 = ldsw(Vbuf, 32 + lo, hi * 16 + c * 32);
      ov[0] = mfma32(vf0, pc.h, ov[0]);
      ov[1] = mfma32(vf1, pc.h, ov[1]);
    }
    __syncthreads();
  }

  // epilogue: normalize, bounce through LDS (swizzled) for coalesced stores
  float lt = lsum + __shfl_xor(lsum, 32, 64);
  float inv = 1.0f / lt;
  char* outl = lds + w * 4096;   // per-wave 4KB region: [32 q][64 d] bf16
#pragma unroll
  for (int t2 = 0; t2 < 2; ++t2)
#pragma unroll
    for (int rp = 0; rp < 8; ++rp) {
      const int r = rp * 2;
      const int d0 = (r & 3) + 8 * (r >> 2) + 4 * hi + 32 * t2;
      unsigned pw = cvtpk(ov[t2][r] * inv, ov[t2][r + 1] * inv);
      *(unsigned*)(outl + lo * 128 + ((d0 * 2) ^ ((lo & 7) << 4))) = pw;
    }
  __syncthreads();
  {
    const int qi = l >> 1, cbb = (l & 1) * 64;
    const int t = q0 + 8 * qi + w;
    unsigned short* gp = og + ((size_t)(b * 2048 + t)) * 1024 + h * 64 + (cbb >> 1);
#pragma unroll
    for (int i = 0; i < 4; ++i) {
      uint4 vdat = *(const uint4*)(outl + qi * 128 + ((cbb + i * 16) ^ ((qi & 7) << 4)));
      *(uint4*)(gp + i * 8) = vdat;
    }
  }
}

extern "C" void kernel_launch(void* const* d_in, const int* in_sizes, int n_in,
                              void* d_out, int out_size, void* d_ws, size_t ws_size,
                              hipStream_t stream) {
  const float* x = (const float*)d_in[0];
  const float* Wqkv = (const float*)d_in[1];
  const float* Wout = (const float*)d_in[2];
  const float* bout = (const float*)d_in[3];
  float* out = (float*)d_out;
  char* ws = (char*)d_ws;

  unsigned short* xb = (unsigned short*)(ws);
  unsigned short* wqb = (unsigned short*)(ws + 16777216);
  unsigned short* wob = (unsigned short*)(ws + 23068672);
  unsigned short* qb = (unsigned short*)(ws + 25165824);
  unsigned short* kb = (unsigned short*)(ws + 41943040);
  unsigned short* vb = (unsigned short*)(ws + 58720256);
  unsigned short* vtb = xb;   // x dead after QKV GEMM
  unsigned short* ogb = vb;   // v dead after transpose

  cast_f32_bf16<<<8192, 256, 0, stream>>>(x, xb, 8388608);
  cast_f32_bf16<<<3072, 256, 0, stream>>>(Wqkv, wqb, 3145728);
  cast_f32_bf16<<<1024, 256, 0, stream>>>(Wout, wob, 1048576);

  gemm_bt<0><<<dim3(24, 64), 256, 0, stream>>>(xb, wqb, qb, kb, vb, nullptr, nullptr);
  transpose_v64<<<dim3(32, 64), 256, 0, stream>>>(vb, vtb);
  attn_causal<<<dim3(64, 8), 512, 0, stream>>>(qb, kb, vtb, ogb);
  gemm_bt<1><<<dim3(8, 64), 256, 0, stream>>>(ogb, wob, nullptr, nullptr, nullptr, bout, out);
}